// Round 1
// baseline (2101.233 us; speedup 1.0000x reference)
//
#include <hip/hip_runtime.h>

// GCN2: h1 = relu(gcn(x,W1,b1)); h2 = relu(gcn(h1,W2,b2)); out = h2@Wlin+blin
// gcn(x,W,b)[d] = dinv[d] * sum_{s->d, incl self} (x[s]@W) * dinv[s] + b
// We fold dinv[s] into the transformed features ("h'"), scatter pure sums,
// and apply dinv[d] + bias + relu when the aggregate is consumed.

constexpr int FDIM = 128;
constexpr int CDIM = 40;

static inline size_t AL512(size_t x) { return (x + 511) & ~size_t(511); }

__global__ void k_deg(const int* __restrict__ dst, int* __restrict__ deg, int E) {
    int e = blockIdx.x * blockDim.x + threadIdx.x;
    if (e < E) atomicAdd(&deg[dst[e]], 1);
}

__global__ void k_dinv(const int* __restrict__ deg, float* __restrict__ dinv, int n) {
    int i = blockIdx.x * blockDim.x + threadIdx.x;
    if (i < n) dinv[i] = rsqrtf((float)deg[i] + 1.0f);  // +1 = self loop, deg>0 always
}

// Hp[r][c] = (X[r] @ W)[c] * dinv[r]   (X: n x 128, W: 128 x 128)
__global__ __launch_bounds__(256) void k_gemm1(const float* __restrict__ X,
        const float* __restrict__ W, const float* __restrict__ dinv,
        float* __restrict__ Hp, int n) {
    __shared__ float xs[16][128];
    int t = threadIdx.x;
    int r0 = blockIdx.x * 16;
    for (int i = t; i < 16 * 128; i += 256) {
        int r = i >> 7, c = i & 127;
        int gr = r0 + r;
        xs[r][c] = (gr < n) ? X[(size_t)gr * 128 + c] : 0.f;
    }
    __syncthreads();
    int col = t & 127, half = t >> 7;
    float acc[8];
#pragma unroll
    for (int j = 0; j < 8; ++j) acc[j] = 0.f;
    for (int k = 0; k < 128; ++k) {
        float w = W[k * 128 + col];
#pragma unroll
        for (int j = 0; j < 8; ++j) acc[j] += xs[half + 2 * j][k] * w;
    }
#pragma unroll
    for (int j = 0; j < 8; ++j) {
        int gr = r0 + half + 2 * j;
        if (gr < n) Hp[(size_t)gr * 128 + col] = acc[j] * dinv[gr];
    }
}

// agg[dst] += h[src] for all edges + self loops (e >= E -> s=d=e-E)
template <int D>
__global__ __launch_bounds__(256) void k_scatter(const int* __restrict__ src,
        const int* __restrict__ dst, const float* __restrict__ h,
        float* __restrict__ agg, int E, int total) {
    constexpr int TPE = D / 4;
    int idx = blockIdx.x * blockDim.x + threadIdx.x;
    int e = idx / TPE;
    if (e >= total) return;
    int f = (idx % TPE) * 4;
    int s, d;
    if (e < E) { s = src[e]; d = dst[e]; } else { s = d = e - E; }
    const float4 v = *reinterpret_cast<const float4*>(&h[(size_t)s * D + f]);
    float* a = &agg[(size_t)d * D + f];
    unsafeAtomicAdd(a + 0, v.x);
    unsafeAtomicAdd(a + 1, v.y);
    unsafeAtomicAdd(a + 2, v.z);
    unsafeAtomicAdd(a + 3, v.w);
}

// hp[r][c] = ( relu(dinv[r]*agg1[r] + b1) @ W2 )[c] * dinv[r]   (W2: 128 x 40)
__global__ __launch_bounds__(320) void k_gemm2(const float* __restrict__ agg1,
        const float* __restrict__ b1, const float* __restrict__ W2,
        const float* __restrict__ dinv, float* __restrict__ hp, int n) {
    __shared__ float xs[8][129];  // +1 pad: avoid 8-way bank conflict on xs[r][k]
    int t = threadIdx.x;
    int r0 = blockIdx.x * 8;
    for (int i = t; i < 8 * 128; i += 320) {
        int r = i >> 7, c = i & 127;
        int gr = r0 + r;
        xs[r][c] = (gr < n) ? fmaxf(fmaf(dinv[gr], agg1[(size_t)gr * 128 + c], b1[c]), 0.f)
                            : 0.f;
    }
    __syncthreads();
    int col = t % 40, r = t / 40;  // 320 threads -> r in [0,8)
    float acc = 0.f;
#pragma unroll
    for (int k = 0; k < 128; ++k) acc += xs[r][k] * W2[k * 40 + col];
    int gr = r0 + r;
    if (gr < n) hp[(size_t)gr * 40 + col] = acc * dinv[gr];
}

// h2 = relu(dinv[r]*agg2[r] + b2)  -> h2_out ; lin_out = h2 @ Wlin + blin
__global__ __launch_bounds__(256) void k_final(const float* __restrict__ agg2,
        const float* __restrict__ b2, const float* __restrict__ Wlin,
        const float* __restrict__ blin, const float* __restrict__ dinv,
        float* __restrict__ h2_out, float* __restrict__ lin_out, int n) {
    __shared__ float wl[CDIM * CDIM];
    __shared__ float hs[32 * CDIM];
    int t = threadIdx.x;
    int r0 = blockIdx.x * 32;
    for (int i = t; i < CDIM * CDIM; i += 256) wl[i] = Wlin[i];
    for (int i = t; i < 32 * CDIM; i += 256) {
        int r = i / CDIM, c = i % CDIM;
        int gr = r0 + r;
        float v = 0.f;
        if (gr < n) {
            v = fmaxf(fmaf(dinv[gr], agg2[(size_t)gr * CDIM + c], b2[c]), 0.f);
            h2_out[(size_t)gr * CDIM + c] = v;
        }
        hs[i] = v;
    }
    __syncthreads();
    for (int i = t; i < 32 * CDIM; i += 256) {
        int r = i / CDIM, c = i % CDIM;
        int gr = r0 + r;
        if (gr >= n) continue;
        float acc = blin[c];
#pragma unroll
        for (int k = 0; k < CDIM; ++k) acc += hs[r * CDIM + k] * wl[k * CDIM + c];
        lin_out[(size_t)gr * CDIM + c] = acc;
    }
}

extern "C" void kernel_launch(void* const* d_in, const int* in_sizes, int n_in,
                              void* d_out, int out_size, void* d_ws, size_t ws_size,
                              hipStream_t stream) {
    const float* x    = (const float*)d_in[0];
    const int*   ei   = (const int*)d_in[1];
    const float* W1   = (const float*)d_in[2];
    const float* b1   = (const float*)d_in[3];
    const float* W2   = (const float*)d_in[4];
    const float* b2   = (const float*)d_in[5];
    const float* Wlin = (const float*)d_in[6];
    const float* blin = (const float*)d_in[7];
    float* out = (float*)d_out;

    const int n = in_sizes[0] / FDIM;
    const int E = in_sizes[1] / 2;
    const int* src = ei;
    const int* dst = ei + E;
    const int tot = E + n;  // edges + self loops

    char* ws = (char*)d_ws;
    size_t off = 0;
    int*   deg  = (int*)(ws + off);   off = AL512(off + (size_t)n * 4);
    float* dinv = (float*)(ws + off); off = AL512(off + (size_t)n * 4);
    float* bufA = (float*)(ws + off); off = AL512(off + (size_t)n * FDIM * 4);  // h' then agg2
    float* bufB = (float*)(ws + off); off = AL512(off + (size_t)n * FDIM * 4);  // agg1
    float* hp   = (float*)(ws + off); off = AL512(off + (size_t)n * CDIM * 4);  // h2'pre
    (void)ws_size; (void)n_in; (void)out_size;

    float* h2_out  = out;
    float* lin_out = out + (size_t)n * CDIM;

    hipMemsetAsync(deg, 0, (size_t)n * 4, stream);
    k_deg<<<(E + 255) / 256, 256, 0, stream>>>(dst, deg, E);
    k_dinv<<<(n + 255) / 256, 256, 0, stream>>>(deg, dinv, n);

    // conv1
    k_gemm1<<<(n + 15) / 16, 256, 0, stream>>>(x, W1, dinv, bufA, n);
    hipMemsetAsync(bufB, 0, (size_t)n * FDIM * 4, stream);
    {
        long th = (long)tot * (FDIM / 4);
        k_scatter<FDIM><<<(unsigned)((th + 255) / 256), 256, 0, stream>>>(src, dst, bufA, bufB, E, tot);
    }

    // conv2 (bias+relu+dinv fused into GEMM2 load)
    k_gemm2<<<(n + 7) / 8, 320, 0, stream>>>(bufB, b1, W2, dinv, hp, n);
    hipMemsetAsync(bufA, 0, (size_t)n * CDIM * 4, stream);
    {
        long th = (long)tot * (CDIM / 4);
        k_scatter<CDIM><<<(unsigned)((th + 255) / 256), 256, 0, stream>>>(src, dst, hp, bufA, E, tot);
    }

    // h2 + linear head
    k_final<<<(n + 31) / 32, 256, 0, stream>>>(bufA, b2, Wlin, blin, dinv, h2_out, lin_out, n);
}

// Round 2
// 317.068 us; speedup vs baseline: 6.6271x; 6.6271x over previous
//
#include <hip/hip_runtime.h>

// GCN2: h1 = relu(gcn(x,W1,b1)); h2 = relu(gcn(h1,W2,b2)); out = h2@Wlin+blin
// gcn(x,W,b)[d] = dinv[d] * sum_{s->d, incl self} (x[s]@W) * dinv[s] + b
// dinv[s] folded into transformed features h'; aggregation is atomic-free:
// CSR (edges sorted by dst) built per call, one wave per dst node gathers.

constexpr int FDIM = 128;
constexpr int CDIM = 40;

static inline size_t AL512(size_t x) { return (x + 511) & ~size_t(511); }

__global__ void k_deg(const int* __restrict__ dst, int* __restrict__ deg, int E) {
    int e = blockIdx.x * blockDim.x + threadIdx.x;
    if (e < E) atomicAdd(&deg[dst[e]], 1);
}

__global__ void k_dinv(const int* __restrict__ deg, float* __restrict__ dinv, int n) {
    int i = blockIdx.x * blockDim.x + threadIdx.x;
    if (i < n) dinv[i] = rsqrtf((float)deg[i] + 1.0f);  // +1 = self loop
}

// --- 3-kernel exclusive scan over deg[] -> offs[], cursor[] ---
__global__ __launch_bounds__(256) void k_scan_block(const int* __restrict__ cnt,
        int* __restrict__ part, int* __restrict__ bsum, int n) {
    __shared__ int tmp[256];
    int i = blockIdx.x * 256 + threadIdx.x;
    int v = (i < n) ? cnt[i] : 0;
    tmp[threadIdx.x] = v;
    __syncthreads();
    for (int o = 1; o < 256; o <<= 1) {
        int t = (threadIdx.x >= o) ? tmp[threadIdx.x - o] : 0;
        __syncthreads();
        tmp[threadIdx.x] += t;
        __syncthreads();
    }
    if (i < n) part[i] = tmp[threadIdx.x] - v;  // exclusive within block
    if (threadIdx.x == 255) bsum[blockIdx.x] = tmp[255];
}

__global__ __launch_bounds__(256) void k_scan_tops(int* __restrict__ bsum, int nb) {
    __shared__ int tmp[256];
    int v = (threadIdx.x < nb) ? bsum[threadIdx.x] : 0;
    tmp[threadIdx.x] = v;
    __syncthreads();
    for (int o = 1; o < 256; o <<= 1) {
        int t = (threadIdx.x >= o) ? tmp[threadIdx.x - o] : 0;
        __syncthreads();
        tmp[threadIdx.x] += t;
        __syncthreads();
    }
    if (threadIdx.x < nb) bsum[threadIdx.x] = tmp[threadIdx.x] - v;
}

__global__ __launch_bounds__(256) void k_scan_add(const int* __restrict__ part,
        const int* __restrict__ bsum, int* __restrict__ offs,
        int* __restrict__ cursor, int n) {
    int i = blockIdx.x * 256 + threadIdx.x;
    if (i < n) {
        int o = part[i] + bsum[blockIdx.x];
        offs[i] = o;
        cursor[i] = o;
    }
}

__global__ void k_fill(const int* __restrict__ src, const int* __restrict__ dst,
        int* __restrict__ cursor, int* __restrict__ ss, int E) {
    int e = blockIdx.x * blockDim.x + threadIdx.x;
    if (e < E) {
        int p = atomicAdd(&cursor[dst[e]], 1);
        ss[p] = src[e];
    }
}

// Hp[r][c] = (X[r] @ W)[c] * dinv[r]   (X: n x 128, W: 128 x 128)
__global__ __launch_bounds__(256) void k_gemm1(const float* __restrict__ X,
        const float* __restrict__ W, const float* __restrict__ dinv,
        float* __restrict__ Hp, int n) {
    __shared__ float xs[16][128];
    int t = threadIdx.x;
    int r0 = blockIdx.x * 16;
    for (int i = t; i < 16 * 128; i += 256) {
        int r = i >> 7, c = i & 127;
        int gr = r0 + r;
        xs[r][c] = (gr < n) ? X[(size_t)gr * 128 + c] : 0.f;
    }
    __syncthreads();
    int col = t & 127, half = t >> 7;
    float acc[8];
#pragma unroll
    for (int j = 0; j < 8; ++j) acc[j] = 0.f;
    for (int k = 0; k < 128; ++k) {
        float w = W[k * 128 + col];
#pragma unroll
        for (int j = 0; j < 8; ++j) acc[j] += xs[half + 2 * j][k] * w;
    }
#pragma unroll
    for (int j = 0; j < 8; ++j) {
        int gr = r0 + half + 2 * j;
        if (gr < n) Hp[(size_t)gr * 128 + col] = acc[j] * dinv[gr];
    }
}

// agg[d] = h'[d] + sum_{s in CSR[d]} h'[s]   (D=128, one wave per node, float2/lane)
__global__ __launch_bounds__(256) void k_agg128(const int* __restrict__ ss,
        const int* __restrict__ offs, const float* __restrict__ hp,
        float* __restrict__ agg, int n, int E) {
    int w = (blockIdx.x * 256 + threadIdx.x) >> 6;
    int lane = threadIdx.x & 63;
    if (w >= n) return;
    int beg = offs[w];
    int end = (w == n - 1) ? E : offs[w + 1];
    const float2* hpv = (const float2*)hp;
    float2 acc = hpv[(size_t)w * 64 + lane];  // self loop
    int j = beg;
    for (; j + 1 < end; j += 2) {
        int s0 = ss[j], s1 = ss[j + 1];
        float2 a = hpv[(size_t)s0 * 64 + lane];
        float2 b = hpv[(size_t)s1 * 64 + lane];
        acc.x += a.x + b.x;
        acc.y += a.y + b.y;
    }
    if (j < end) {
        int s = ss[j];
        float2 a = hpv[(size_t)s * 64 + lane];
        acc.x += a.x;
        acc.y += a.y;
    }
    ((float2*)agg)[(size_t)w * 64 + lane] = acc;
}

// agg[d] = h'[d] + sum h'[s]   (D=40, one wave per node, lanes 0..39 active)
__global__ __launch_bounds__(256) void k_agg40(const int* __restrict__ ss,
        const int* __restrict__ offs, const float* __restrict__ hp,
        float* __restrict__ agg, int n, int E) {
    int w = (blockIdx.x * 256 + threadIdx.x) >> 6;
    int lane = threadIdx.x & 63;
    if (w >= n) return;
    int beg = offs[w];
    int end = (w == n - 1) ? E : offs[w + 1];
    float acc = (lane < CDIM) ? hp[(size_t)w * CDIM + lane] : 0.f;
    int j = beg;
    for (; j + 1 < end; j += 2) {
        int s0 = ss[j], s1 = ss[j + 1];
        if (lane < CDIM) {
            acc += hp[(size_t)s0 * CDIM + lane];
            acc += hp[(size_t)s1 * CDIM + lane];
        }
    }
    if (j < end) {
        int s = ss[j];
        if (lane < CDIM) acc += hp[(size_t)s * CDIM + lane];
    }
    if (lane < CDIM) agg[(size_t)w * CDIM + lane] = acc;
}

// hp[r][c] = ( relu(dinv[r]*agg1[r] + b1) @ W2 )[c] * dinv[r]   (W2: 128 x 40)
__global__ __launch_bounds__(320) void k_gemm2(const float* __restrict__ agg1,
        const float* __restrict__ b1, const float* __restrict__ W2,
        const float* __restrict__ dinv, float* __restrict__ hp, int n) {
    __shared__ float xs[8][129];
    int t = threadIdx.x;
    int r0 = blockIdx.x * 8;
    for (int i = t; i < 8 * 128; i += 320) {
        int r = i >> 7, c = i & 127;
        int gr = r0 + r;
        xs[r][c] = (gr < n) ? fmaxf(fmaf(dinv[gr], agg1[(size_t)gr * 128 + c], b1[c]), 0.f)
                            : 0.f;
    }
    __syncthreads();
    int col = t % 40, r = t / 40;
    float acc = 0.f;
#pragma unroll
    for (int k = 0; k < 128; ++k) acc += xs[r][k] * W2[k * 40 + col];
    int gr = r0 + r;
    if (gr < n) hp[(size_t)gr * 40 + col] = acc * dinv[gr];
}

// h2 = relu(dinv[r]*agg2[r] + b2) -> h2_out ; lin_out = h2 @ Wlin + blin
__global__ __launch_bounds__(256) void k_final(const float* __restrict__ agg2,
        const float* __restrict__ b2, const float* __restrict__ Wlin,
        const float* __restrict__ blin, const float* __restrict__ dinv,
        float* __restrict__ h2_out, float* __restrict__ lin_out, int n) {
    __shared__ float wl[CDIM * CDIM];
    __shared__ float hs[32 * CDIM];
    int t = threadIdx.x;
    int r0 = blockIdx.x * 32;
    for (int i = t; i < CDIM * CDIM; i += 256) wl[i] = Wlin[i];
    for (int i = t; i < 32 * CDIM; i += 256) {
        int r = i / CDIM, c = i % CDIM;
        int gr = r0 + r;
        float v = 0.f;
        if (gr < n) {
            v = fmaxf(fmaf(dinv[gr], agg2[(size_t)gr * CDIM + c], b2[c]), 0.f);
            h2_out[(size_t)gr * CDIM + c] = v;
        }
        hs[i] = v;
    }
    __syncthreads();
    for (int i = t; i < 32 * CDIM; i += 256) {
        int r = i / CDIM, c = i % CDIM;
        int gr = r0 + r;
        if (gr >= n) continue;
        float acc = blin[c];
#pragma unroll
        for (int k = 0; k < CDIM; ++k) acc += hs[r * CDIM + k] * wl[k * CDIM + c];
        lin_out[(size_t)gr * CDIM + c] = acc;
    }
}

extern "C" void kernel_launch(void* const* d_in, const int* in_sizes, int n_in,
                              void* d_out, int out_size, void* d_ws, size_t ws_size,
                              hipStream_t stream) {
    const float* x    = (const float*)d_in[0];
    const int*   ei   = (const int*)d_in[1];
    const float* W1   = (const float*)d_in[2];
    const float* b1   = (const float*)d_in[3];
    const float* W2   = (const float*)d_in[4];
    const float* b2   = (const float*)d_in[5];
    const float* Wlin = (const float*)d_in[6];
    const float* blin = (const float*)d_in[7];
    float* out = (float*)d_out;

    const int n = in_sizes[0] / FDIM;
    const int E = in_sizes[1] / 2;
    const int* src = ei;
    const int* dst = ei + E;

    char* ws = (char*)d_ws;
    size_t off = 0;
    int*   deg    = (int*)(ws + off);   off = AL512(off + (size_t)n * 4);
    float* dinv   = (float*)(ws + off); off = AL512(off + (size_t)n * 4);
    int*   part   = (int*)(ws + off);   off = AL512(off + (size_t)n * 4);
    int*   bsum   = (int*)(ws + off);   off = AL512(off + 256 * 4);
    int*   offs   = (int*)(ws + off);   off = AL512(off + (size_t)n * 4);
    int*   cursor = (int*)(ws + off);   off = AL512(off + (size_t)n * 4);
    int*   ss     = (int*)(ws + off);   off = AL512(off + (size_t)E * 4);
    float* bufA   = (float*)(ws + off); off = AL512(off + (size_t)n * FDIM * 4);  // h1' then agg2
    float* bufB   = (float*)(ws + off); off = AL512(off + (size_t)n * FDIM * 4);  // agg1
    float* hp     = (float*)(ws + off); off = AL512(off + (size_t)n * CDIM * 4);  // h2' pre-agg
    (void)ws_size; (void)n_in; (void)out_size;

    float* h2_out  = out;
    float* lin_out = out + (size_t)n * CDIM;

    const int nb = (n + 255) / 256;

    // degree + dinv + CSR build
    hipMemsetAsync(deg, 0, (size_t)n * 4, stream);
    k_deg<<<(E + 255) / 256, 256, 0, stream>>>(dst, deg, E);
    k_dinv<<<(n + 255) / 256, 256, 0, stream>>>(deg, dinv, n);
    k_scan_block<<<nb, 256, 0, stream>>>(deg, part, bsum, n);
    k_scan_tops<<<1, 256, 0, stream>>>(bsum, nb);
    k_scan_add<<<nb, 256, 0, stream>>>(part, bsum, offs, cursor, n);
    k_fill<<<(E + 255) / 256, 256, 0, stream>>>(src, dst, cursor, ss, E);

    // conv1
    k_gemm1<<<(n + 15) / 16, 256, 0, stream>>>(x, W1, dinv, bufA, n);
    k_agg128<<<(n * 64 + 255) / 256, 256, 0, stream>>>(ss, offs, bufA, bufB, n, E);

    // conv2
    k_gemm2<<<(n + 7) / 8, 320, 0, stream>>>(bufB, b1, W2, dinv, hp, n);
    k_agg40<<<(n * 64 + 255) / 256, 256, 0, stream>>>(ss, offs, hp, bufA, n, E);

    // h2 + linear head
    k_final<<<(n + 31) / 32, 256, 0, stream>>>(bufA, b2, Wlin, blin, dinv, h2_out, lin_out, n);
}

// Round 3
// 269.440 us; speedup vs baseline: 7.7985x; 1.1768x over previous
//
#include <hip/hip_runtime.h>
#include <hip/hip_fp16.h>

// GCN2: h1 = relu(gcn(x,W1,b1)); h2 = relu(gcn(h1,W2,b2)); out = h2@Wlin+blin
// dinv[s] folded into transformed features h' (stored fp16 to halve gather
// bytes); aggregation is atomic-free: CSR (edges by dst) built per call,
// one wave per dst node gathers with fp32 accumulation.

constexpr int FDIM = 128;
constexpr int CDIM = 40;

static inline size_t AL512(size_t x) { return (x + 511) & ~size_t(511); }

__global__ void k_deg(const int* __restrict__ dst, int* __restrict__ deg, int E) {
    int e = blockIdx.x * blockDim.x + threadIdx.x;
    if (e < E) atomicAdd(&deg[dst[e]], 1);
}

// --- exclusive scan over deg[] -> offs[], cursor[]; dinv fused here ---
__global__ __launch_bounds__(256) void k_scan_block(const int* __restrict__ cnt,
        int* __restrict__ part, int* __restrict__ bsum,
        float* __restrict__ dinv, int n) {
    __shared__ int tmp[256];
    int i = blockIdx.x * 256 + threadIdx.x;
    int v = (i < n) ? cnt[i] : 0;
    if (i < n) dinv[i] = rsqrtf((float)v + 1.0f);  // +1 = self loop
    tmp[threadIdx.x] = v;
    __syncthreads();
    for (int o = 1; o < 256; o <<= 1) {
        int t = (threadIdx.x >= o) ? tmp[threadIdx.x - o] : 0;
        __syncthreads();
        tmp[threadIdx.x] += t;
        __syncthreads();
    }
    if (i < n) part[i] = tmp[threadIdx.x] - v;  // exclusive within block
    if (threadIdx.x == 255) bsum[blockIdx.x] = tmp[255];
}

__global__ __launch_bounds__(256) void k_scan_tops(int* __restrict__ bsum, int nb) {
    __shared__ int tmp[256];
    int v = (threadIdx.x < nb) ? bsum[threadIdx.x] : 0;
    tmp[threadIdx.x] = v;
    __syncthreads();
    for (int o = 1; o < 256; o <<= 1) {
        int t = (threadIdx.x >= o) ? tmp[threadIdx.x - o] : 0;
        __syncthreads();
        tmp[threadIdx.x] += t;
        __syncthreads();
    }
    if (threadIdx.x < nb) bsum[threadIdx.x] = tmp[threadIdx.x] - v;
}

__global__ __launch_bounds__(256) void k_scan_add(const int* __restrict__ part,
        const int* __restrict__ bsum, int* __restrict__ offs,
        int* __restrict__ cursor, int n) {
    int i = blockIdx.x * 256 + threadIdx.x;
    if (i < n) {
        int o = part[i] + bsum[blockIdx.x];
        offs[i] = o;
        cursor[i] = o;
    }
}

__global__ void k_fill(const int* __restrict__ src, const int* __restrict__ dst,
        int* __restrict__ cursor, int* __restrict__ ss, int E) {
    int e = blockIdx.x * blockDim.x + threadIdx.x;
    if (e < E) {
        int p = atomicAdd(&cursor[dst[e]], 1);
        ss[p] = src[e];
    }
}

// Hp[r][c] = fp16( (X[r] @ W)[c] * dinv[r] )   (X: n x 128, W: 128 x 128)
__global__ __launch_bounds__(256) void k_gemm1(const float* __restrict__ X,
        const float* __restrict__ W, const float* __restrict__ dinv,
        __half* __restrict__ Hp, int n) {
    __shared__ float xs[16][128];
    int t = threadIdx.x;
    int r0 = blockIdx.x * 16;
    for (int i = t; i < 16 * 128; i += 256) {
        int r = i >> 7, c = i & 127;
        int gr = r0 + r;
        xs[r][c] = (gr < n) ? X[(size_t)gr * 128 + c] : 0.f;
    }
    __syncthreads();
    int col = t & 127, half = t >> 7;
    float acc[8];
#pragma unroll
    for (int j = 0; j < 8; ++j) acc[j] = 0.f;
    for (int k = 0; k < 128; ++k) {
        float w = W[k * 128 + col];
#pragma unroll
        for (int j = 0; j < 8; ++j) acc[j] += xs[half + 2 * j][k] * w;
    }
#pragma unroll
    for (int j = 0; j < 8; ++j) {
        int gr = r0 + half + 2 * j;
        if (gr < n) Hp[(size_t)gr * 128 + col] = __float2half(acc[j] * dinv[gr]);
    }
}

// agg[d] = h'[d] + sum_{s in CSR[d]} h'[s]  (D=128 fp16 rows, one wave/node,
// half2 per lane = 256B/row, fp32 accumulate, unroll 4)
__global__ __launch_bounds__(256) void k_agg128(const int* __restrict__ ss,
        const int* __restrict__ offs, const __half* __restrict__ hp,
        float* __restrict__ agg, int n, int E) {
    int w = (blockIdx.x * 256 + threadIdx.x) >> 6;
    int lane = threadIdx.x & 63;
    if (w >= n) return;
    int beg = offs[w];
    int end = (w == n - 1) ? E : offs[w + 1];
    const __half2* hpv = (const __half2*)hp;
    float2 acc = __half22float2(hpv[(size_t)w * 64 + lane]);  // self loop
    int j = beg;
    for (; j + 3 < end; j += 4) {
        int s0 = ss[j], s1 = ss[j + 1], s2 = ss[j + 2], s3 = ss[j + 3];
        float2 a = __half22float2(hpv[(size_t)s0 * 64 + lane]);
        float2 b = __half22float2(hpv[(size_t)s1 * 64 + lane]);
        float2 c = __half22float2(hpv[(size_t)s2 * 64 + lane]);
        float2 d = __half22float2(hpv[(size_t)s3 * 64 + lane]);
        acc.x += (a.x + b.x) + (c.x + d.x);
        acc.y += (a.y + b.y) + (c.y + d.y);
    }
    for (; j < end; ++j) {
        int s = ss[j];
        float2 a = __half22float2(hpv[(size_t)s * 64 + lane]);
        acc.x += a.x;
        acc.y += a.y;
    }
    ((float2*)agg)[(size_t)w * 64 + lane] = acc;
}

// agg[d] = h'[d] + sum h'[s]  (D=40 fp16 rows, one wave/node, lanes 0..39)
__global__ __launch_bounds__(256) void k_agg40(const int* __restrict__ ss,
        const int* __restrict__ offs, const __half* __restrict__ hp,
        float* __restrict__ agg, int n, int E) {
    int w = (blockIdx.x * 256 + threadIdx.x) >> 6;
    int lane = threadIdx.x & 63;
    if (w >= n) return;
    int beg = offs[w];
    int end = (w == n - 1) ? E : offs[w + 1];
    bool act = lane < CDIM;
    float acc = act ? __half2float(hp[(size_t)w * CDIM + lane]) : 0.f;
    int j = beg;
    for (; j + 3 < end; j += 4) {
        int s0 = ss[j], s1 = ss[j + 1], s2 = ss[j + 2], s3 = ss[j + 3];
        if (act) {
            float a = __half2float(hp[(size_t)s0 * CDIM + lane]);
            float b = __half2float(hp[(size_t)s1 * CDIM + lane]);
            float c = __half2float(hp[(size_t)s2 * CDIM + lane]);
            float d = __half2float(hp[(size_t)s3 * CDIM + lane]);
            acc += (a + b) + (c + d);
        }
    }
    for (; j < end; ++j) {
        int s = ss[j];
        if (act) acc += __half2float(hp[(size_t)s * CDIM + lane]);
    }
    if (act) agg[(size_t)w * CDIM + lane] = acc;
}

// hp[r][c] = fp16( ( relu(dinv[r]*agg1[r] + b1) @ W2 )[c] * dinv[r] )
__global__ __launch_bounds__(320) void k_gemm2(const float* __restrict__ agg1,
        const float* __restrict__ b1, const float* __restrict__ W2,
        const float* __restrict__ dinv, __half* __restrict__ hp, int n) {
    __shared__ float xs[8][129];
    int t = threadIdx.x;
    int r0 = blockIdx.x * 8;
    for (int i = t; i < 8 * 128; i += 320) {
        int r = i >> 7, c = i & 127;
        int gr = r0 + r;
        xs[r][c] = (gr < n) ? fmaxf(fmaf(dinv[gr], agg1[(size_t)gr * 128 + c], b1[c]), 0.f)
                            : 0.f;
    }
    __syncthreads();
    int col = t % 40, r = t / 40;
    float acc = 0.f;
#pragma unroll
    for (int k = 0; k < 128; ++k) acc += xs[r][k] * W2[k * 40 + col];
    int gr = r0 + r;
    if (gr < n) hp[(size_t)gr * 40 + col] = __float2half(acc * dinv[gr]);
}

// h2 = relu(dinv[r]*agg2[r] + b2) -> h2_out ; lin_out = h2 @ Wlin + blin
__global__ __launch_bounds__(256) void k_final(const float* __restrict__ agg2,
        const float* __restrict__ b2, const float* __restrict__ Wlin,
        const float* __restrict__ blin, const float* __restrict__ dinv,
        float* __restrict__ h2_out, float* __restrict__ lin_out, int n) {
    __shared__ float wl[CDIM * CDIM];
    __shared__ float hs[32 * CDIM];
    int t = threadIdx.x;
    int r0 = blockIdx.x * 32;
    for (int i = t; i < CDIM * CDIM; i += 256) wl[i] = Wlin[i];
    for (int i = t; i < 32 * CDIM; i += 256) {
        int r = i / CDIM, c = i % CDIM;
        int gr = r0 + r;
        float v = 0.f;
        if (gr < n) {
            v = fmaxf(fmaf(dinv[gr], agg2[(size_t)gr * CDIM + c], b2[c]), 0.f);
            h2_out[(size_t)gr * CDIM + c] = v;
        }
        hs[i] = v;
    }
    __syncthreads();
    for (int i = t; i < 32 * CDIM; i += 256) {
        int r = i / CDIM, c = i % CDIM;
        int gr = r0 + r;
        if (gr >= n) continue;
        float acc = blin[c];
#pragma unroll
        for (int k = 0; k < CDIM; ++k) acc += hs[r * CDIM + k] * wl[k * CDIM + c];
        lin_out[(size_t)gr * CDIM + c] = acc;
    }
}

extern "C" void kernel_launch(void* const* d_in, const int* in_sizes, int n_in,
                              void* d_out, int out_size, void* d_ws, size_t ws_size,
                              hipStream_t stream) {
    const float* x    = (const float*)d_in[0];
    const int*   ei   = (const int*)d_in[1];
    const float* W1   = (const float*)d_in[2];
    const float* b1   = (const float*)d_in[3];
    const float* W2   = (const float*)d_in[4];
    const float* b2   = (const float*)d_in[5];
    const float* Wlin = (const float*)d_in[6];
    const float* blin = (const float*)d_in[7];
    float* out = (float*)d_out;

    const int n = in_sizes[0] / FDIM;
    const int E = in_sizes[1] / 2;
    const int* src = ei;
    const int* dst = ei + E;

    char* ws = (char*)d_ws;
    size_t off = 0;
    int*    deg    = (int*)(ws + off);    off = AL512(off + (size_t)n * 4);
    float*  dinv   = (float*)(ws + off);  off = AL512(off + (size_t)n * 4);
    int*    part   = (int*)(ws + off);    off = AL512(off + (size_t)n * 4);
    int*    bsum   = (int*)(ws + off);    off = AL512(off + 256 * 4);
    int*    offs   = (int*)(ws + off);    off = AL512(off + (size_t)n * 4);
    int*    cursor = (int*)(ws + off);    off = AL512(off + (size_t)n * 4);
    int*    ss     = (int*)(ws + off);    off = AL512(off + (size_t)E * 4);
    __half* hp1    = (__half*)(ws + off); off = AL512(off + (size_t)n * FDIM * 2); // h1' fp16
    float*  agg1   = (float*)(ws + off);  off = AL512(off + (size_t)n * FDIM * 4);
    __half* hp2    = (__half*)(ws + off); off = AL512(off + (size_t)n * CDIM * 2); // h2' fp16
    float*  agg2   = (float*)(ws + off);  off = AL512(off + (size_t)n * CDIM * 4);
    (void)ws_size; (void)n_in; (void)out_size;

    float* h2_out  = out;
    float* lin_out = out + (size_t)n * CDIM;

    const int nb = (n + 255) / 256;

    // degree + dinv + CSR build
    hipMemsetAsync(deg, 0, (size_t)n * 4, stream);
    k_deg<<<(E + 255) / 256, 256, 0, stream>>>(dst, deg, E);
    k_scan_block<<<nb, 256, 0, stream>>>(deg, part, bsum, dinv, n);
    k_scan_tops<<<1, 256, 0, stream>>>(bsum, nb);
    k_scan_add<<<nb, 256, 0, stream>>>(part, bsum, offs, cursor, n);
    k_fill<<<(E + 255) / 256, 256, 0, stream>>>(src, dst, cursor, ss, E);

    // conv1
    k_gemm1<<<(n + 15) / 16, 256, 0, stream>>>(x, W1, dinv, hp1, n);
    k_agg128<<<(n * 64 + 255) / 256, 256, 0, stream>>>(ss, offs, hp1, agg1, n, E);

    // conv2
    k_gemm2<<<(n + 7) / 8, 320, 0, stream>>>(agg1, b1, W2, dinv, hp2, n);
    k_agg40<<<(n * 64 + 255) / 256, 256, 0, stream>>>(ss, offs, hp2, agg2, n, E);

    // h2 + linear head
    k_final<<<(n + 31) / 32, 256, 0, stream>>>(agg2, b2, Wlin, blin, dinv, h2_out, lin_out, n);
}